// Round 5
// baseline (1940.091 us; speedup 1.0000x reference)
//
#include <hip/hip_runtime.h>
#include <hip/hip_fp16.h>

#define C 128
#define KORD 6
#define KD (KORD * C)  // 768 fused reduction dim
#define EPB 2048       // edges per block in phase-1
#define NPBLK 2048     // persistent matvec grid: 8 blocks/CU x 256 CU, all co-resident

typedef __attribute__((ext_vector_type(8))) short short8;   // 8 bf16
typedef __attribute__((ext_vector_type(4))) float f32x4;

// ---------- fp32 -> bf16 (RNE) ----------
__device__ __forceinline__ short f2bf(float f) {
  unsigned u = __float_as_uint(f);
  unsigned r = (u + 0x7fffu + ((u >> 16) & 1u)) >> 16;
  return (short)r;
}
__device__ __forceinline__ float bf2f(short s) {
  return __uint_as_float(((unsigned)(unsigned short)s) << 16);
}

// ---------- monotone float<->uint encoding for atomicMax over floats ----------
__device__ __forceinline__ unsigned enc_f32(float f) {
  unsigned u = __float_as_uint(f);
  return (u & 0x80000000u) ? ~u : (u | 0x80000000u);
}
__device__ __forceinline__ float dec_f32(unsigned u) {
  return (u & 0x80000000u) ? __uint_as_float(u ^ 0x80000000u) : __uint_as_float(~u);
}

// ---------- fused: Wt transpose + bsum + nodes->bf16 slot0 + zero flags ----------
__global__ void prep_kernel(const float* __restrict__ W, const float* __restrict__ bd,
                            const float* __restrict__ bias, short* __restrict__ Wt,
                            float* __restrict__ bsum, const float* __restrict__ nodes,
                            short* __restrict__ xb, int n, unsigned* __restrict__ umax,
                            int* __restrict__ bar) {
  int i = blockIdx.x * blockDim.x + threadIdx.x;
  if (i == 0) {
    umax[0] = 0u;   // running max (enc)
    umax[1] = 0u;   // ticket
    bar[0] = 0;     // persistent-kernel barrier counter
  }
  if (i < KD * C) {
    int k = i >> 7, nn = i & 127;
    Wt[(size_t)nn * KD + k] = f2bf(W[i]);
  }
  if (i < C) {
    float s = bias[i];
#pragma unroll
    for (int k = 0; k < KORD; ++k) s += bd[k * C + i];
    bsum[i] = s;
  }
  if (i < n * 32) {
    int row = i >> 5, c4 = i & 31;
    float4 v = ((const float4*)nodes)[(size_t)row * 32 + c4];
    short4 o;
    o.x = f2bf(v.x); o.y = f2bf(v.y); o.z = f2bf(v.z); o.w = f2bf(v.w);
    ((short4*)(xb + (size_t)row * KD))[c4] = o;
  }
}

// ---------- phase 1a: coarse bucket histogram (LDS atomics only) + max(-w) ----------
__global__ __launch_bounds__(256) void p1_count_kernel(const int* __restrict__ senders,
                                                       const float* __restrict__ edges, int ne,
                                                       int* __restrict__ hist, int NB,
                                                       unsigned* __restrict__ umax) {
  __shared__ int h[256];
  int t = threadIdx.x;
  h[t] = 0;
  __syncthreads();
  int base = blockIdx.x * EPB;
  int end = min(base + EPB, ne);
  float m = -INFINITY;
  for (int i = base + t; i < end; i += 256) {
    atomicAdd(&h[senders[i] >> 8], 1);
    m = fmaxf(m, -edges[i]);
  }
#pragma unroll
  for (int off = 32; off > 0; off >>= 1) m = fmaxf(m, __shfl_down(m, off, 64));
  if ((t & 63) == 0) atomicMax(umax, enc_f32(m));
  __syncthreads();
  hist[t * NB + blockIdx.x] = h[t];
}

// ---------- multiblock exclusive scan, stage 1 ----------
__global__ __launch_bounds__(1024) void scan1_kernel(const int* __restrict__ counts,
                                                     int* __restrict__ offsets,
                                                     int* __restrict__ bsums, int n) {
  int t = threadIdx.x;
  int i = blockIdx.x * 1024 + t;
  int lane = t & 63, w = t >> 6;
  int v = (i < n) ? counts[i] : 0;
  int s = v;
#pragma unroll
  for (int d = 1; d < 64; d <<= 1) {
    int o = __shfl_up(s, d, 64);
    if (lane >= d) s += o;
  }
  __shared__ int wsum[16];
  if (lane == 63) wsum[w] = s;
  __syncthreads();
  if (t < 16) {
    int ws = wsum[t];
#pragma unroll
    for (int d = 1; d < 16; d <<= 1) {
      int o = __shfl_up(ws, d, 64);
      if (t >= d) ws += o;
    }
    wsum[t] = ws;
  }
  __syncthreads();
  int excl = s - v + (w > 0 ? wsum[w - 1] : 0);
  if (i < n) offsets[i] = excl;
  if (t == 1023) bsums[blockIdx.x] = wsum[15];
}

// ---------- stage 2: scan of block sums (nb <= 1024) ----------
__global__ __launch_bounds__(1024) void scan2_kernel(int* __restrict__ bsums, int nb) {
  int t = threadIdx.x;
  int lane = t & 63, w = t >> 6;
  int v = (t < nb) ? bsums[t] : 0;
  int s = v;
#pragma unroll
  for (int d = 1; d < 64; d <<= 1) {
    int o = __shfl_up(s, d, 64);
    if (lane >= d) s += o;
  }
  __shared__ int wsum[16];
  if (lane == 63) wsum[w] = s;
  __syncthreads();
  if (t < 16) {
    int ws = wsum[t];
#pragma unroll
    for (int d = 1; d < 16; d <<= 1) {
      int o = __shfl_up(ws, d, 64);
      if (t >= d) ws += o;
    }
    wsum[t] = ws;
  }
  __syncthreads();
  int excl = s - v + (w > 0 ? wsum[w - 1] : 0);
  if (t < nb) bsums[t] = excl;
}

// ---------- phase 1b: scatter into coarse buckets; applies bsums (scan3 folded) ----------
__global__ __launch_bounds__(256) void p1_scatter_kernel(
    const int* __restrict__ senders, const int* __restrict__ receivers,
    const float* __restrict__ edges, int ne, const int* __restrict__ scanned,
    const int* __restrict__ bsums, int NB, int2* __restrict__ bkt) {
  __shared__ int basec[256];
  int t = threadIdx.x;
  int idx = t * NB + blockIdx.x;
  basec[t] = scanned[idx] + bsums[idx >> 10];
  __syncthreads();
  int base = blockIdx.x * EPB;
  int end = min(base + EPB, ne);
  for (int i = base + t; i < end; i += 256) {
    int s = senders[i];
    int pos = atomicAdd(&basec[s >> 8], 1);
    int2 rec;
    rec.x = __float_as_int(edges[i]);
    rec.y = receivers[i] | ((s & 255) << 16);
    bkt[pos] = rec;
  }
}

// ---------- phase 2: CSR finalize + offsets + deg + deg-max + (last block) scale ----------
// csr entry is 32 bits: [w_f16 << 16 | recv_u16]. deg accumulates the
// f16-ROUNDED weight (perturbed-graph consistency, err ~2^-12).
__global__ __launch_bounds__(256) void p2_finalize_kernel(
    const int2* __restrict__ bkt, const int* __restrict__ scanned,
    const int* __restrict__ bsums, int NB, int NBUCK, int ne, int n,
    unsigned* __restrict__ csr_wr, int* __restrict__ offsets, float* __restrict__ degf,
    unsigned* __restrict__ umax, int* __restrict__ ticket, float* __restrict__ scalep) {
  __shared__ int h[256];
  __shared__ int cur[256];
  __shared__ float dg[256];
  __shared__ int wsum[4];
  __shared__ float wmax[4];
  int t = threadIdx.x;
  int b = blockIdx.x;
  int i0 = b * NB;
  int base = scanned[i0] + bsums[i0 >> 10];
  int bend = ne;
  if (b != NBUCK - 1) {
    int i1 = (b + 1) * NB;
    bend = scanned[i1] + bsums[i1 >> 10];
  }
  h[t] = 0;
  dg[t] = 0.f;
  __syncthreads();
  for (int i = base + t; i < bend; i += 256) atomicAdd(&h[(bkt[i].y >> 16) & 255], 1);
  __syncthreads();
  int lane = t & 63, w = t >> 6;
  int v = h[t];
  int s = v;
#pragma unroll
  for (int d = 1; d < 64; d <<= 1) {
    int o = __shfl_up(s, d, 64);
    if (lane >= d) s += o;
  }
  if (lane == 63) wsum[w] = s;
  __syncthreads();
  int carry = 0;
#pragma unroll
  for (int j = 0; j < 4; ++j) carry += (j < w) ? wsum[j] : 0;
  int excl = s - v + carry;
  int node = b * 256 + t;
  if (node < n) offsets[node] = base + excl;
  cur[t] = base + excl;
  __syncthreads();
  for (int i = base + t; i < bend; i += 256) {
    int2 rec = bkt[i];
    int bin = (rec.y >> 16) & 255;
    int pos = atomicAdd(&cur[bin], 1);
    __half hh = __float2half(__int_as_float(rec.x));
    csr_wr[pos] = (unsigned)(rec.y & 0xFFFF) | ((unsigned)__half_as_ushort(hh) << 16);
    atomicAdd(&dg[bin], __half2float(hh));
  }
  __syncthreads();
  float d = dg[t];
  if (node < n) degf[node] = d;
  float m = (node < n) ? d : 0.f;
#pragma unroll
  for (int off = 32; off > 0; off >>= 1) m = fmaxf(m, __shfl_down(m, off, 64));
  if (lane == 0) wmax[w] = m;
  __syncthreads();
  if (t == 0) {
    float mm = fmaxf(fmaxf(wmax[0], wmax[1]), fmaxf(wmax[2], wmax[3]));
    atomicMax(umax, enc_f32(mm));
    if (b == NBUCK - 1) offsets[n] = ne;
    __threadfence();  // publish umax before taking a ticket
    int done = atomicAdd(ticket, 1);
    if (done == NBUCK - 1) {
      unsigned cu = atomicMax(umax, 0u);
      scalep[0] = 1.0f / dec_f32(cu);
    }
  }
}

// ---------- persistent 5-round Chebyshev matvec (ONE launch, 4 grid barriers) ----------
// R5: replaces 5 dependent dispatches of 12500 blocks. Grid = NPBLK=2048
// blocks of 256, __launch_bounds__(256,8) caps VGPR at 64 + zero LDS -> 8
// blocks/CU guaranteed -> all 2048 co-resident (same 8192 resident waves as
// the multi-launch version; each wave walks ~6 nodes grid-stride).
// Barrier: monotonic agent-scope arrival counter + __threadfence (emits the
// CDNA4 L2 writeback/invalidate needed for cross-XCD visibility — same cache
// ops a kernel boundary performs). s_memrealtime timeout (~50ms) guarantees
// no hang even if residency assumption ever breaks (wrong answer, not a hung
// container — R4 lesson). NO cooperative launch: graph-capture-safe.
__global__ __launch_bounds__(256, 8) void matvec5_kernel(
    short* __restrict__ Xb, const float* __restrict__ deg, const int* __restrict__ offsets,
    const unsigned* __restrict__ csr_wr, const float* __restrict__ scalep, int n,
    int* __restrict__ bar) {
  int t = threadIdx.x;
  int lane = t & 63;
  int sub = lane & 15;
  int quarter = lane >> 4;
  int wid0 = (blockIdx.x * 256 + t) >> 6;
  const int nwaves = NPBLK * 4;
  float inv = scalep[0];  // = 2 / lambda_max

  for (int r = 0; r < 5; ++r) {
    const short* xg = Xb + r * C;
    const short* zg = (r == 0) ? (const short*)0 : Xb + (r - 1) * C;
    short* yg = Xb + (r + 1) * C;
    float sc = (r == 0) ? inv : 2.0f * inv;

    for (int node = wid0; node < n; node += nwaves) {
      int e0 = offsets[node], e1 = offsets[node + 1];
      float d = 0.f;
      short8 xo = {0, 0, 0, 0, 0, 0, 0, 0};
      short8 zv = {0, 0, 0, 0, 0, 0, 0, 0};
      if (quarter == 0) {
        d = deg[node];
        xo = *(const short8*)(xg + (size_t)node * KD + sub * 8);
        if (zg) zv = *(const short8*)(zg + (size_t)node * KD + sub * 8);
      }
      float a[8];
#pragma unroll
      for (int j = 0; j < 8; ++j) a[j] = 0.f;
      int elast = e1 - 1;
      const short* xs = xg + sub * 8;
      for (int e = e0 + quarter; e < e1; e += 16) {
        int eb1 = e + 4, eb2 = e + 8, eb3 = e + 12;
        unsigned p0 = csr_wr[e];
        unsigned p1 = csr_wr[min(eb1, elast)];
        unsigned p2 = csr_wr[min(eb2, elast)];
        unsigned p3 = csr_wr[min(eb3, elast)];
        short8 v0 = *(const short8*)(xs + (p0 & 0xFFFFu) * KD);
        short8 v1 = *(const short8*)(xs + (p1 & 0xFFFFu) * KD);
        short8 v2 = *(const short8*)(xs + (p2 & 0xFFFFu) * KD);
        short8 v3 = *(const short8*)(xs + (p3 & 0xFFFFu) * KD);
        float w0 = __half2float(__ushort_as_half((unsigned short)(p0 >> 16)));
        float w1 = (eb1 < e1) ? __half2float(__ushort_as_half((unsigned short)(p1 >> 16))) : 0.f;
        float w2 = (eb2 < e1) ? __half2float(__ushort_as_half((unsigned short)(p2 >> 16))) : 0.f;
        float w3 = (eb3 < e1) ? __half2float(__ushort_as_half((unsigned short)(p3 >> 16))) : 0.f;
#pragma unroll
        for (int j = 0; j < 8; ++j) {
          float t0 = fmaf(w0, bf2f(v0[j]), a[j]);
          float t1 = fmaf(w1, bf2f(v1[j]), t0);
          float t2 = fmaf(w2, bf2f(v2[j]), t1);
          a[j] = fmaf(w3, bf2f(v3[j]), t2);
        }
      }
#pragma unroll
      for (int j = 0; j < 8; ++j) {
        a[j] += __shfl_xor(a[j], 16, 64);
        a[j] += __shfl_xor(a[j], 32, 64);
      }
      if (quarter == 0) {
        float rr[8];
#pragma unroll
        for (int j = 0; j < 8; ++j) rr[j] = sc * fmaf(d, bf2f(xo[j]), -a[j]);
        if (zg) {
#pragma unroll
          for (int j = 0; j < 8; ++j) rr[j] -= bf2f(zv[j]);
        }
        short8 o;
#pragma unroll
        for (int j = 0; j < 8; ++j) o[j] = f2bf(rr[j]);
        *(short8*)(yg + (size_t)node * KD + sub * 8) = o;
      }
    }

    if (r < 4) {  // grid barrier between rounds
      __syncthreads();
      if (t == 0) {
        __threadfence();  // release: L2 writeback -> cross-XCD visibility
        __hip_atomic_fetch_add(bar, 1, __ATOMIC_ACQ_REL, __HIP_MEMORY_SCOPE_AGENT);
        int target = NPBLK * (r + 1);
        unsigned long long t0 = __builtin_amdgcn_s_memrealtime();
        while (__hip_atomic_load(bar, __ATOMIC_ACQUIRE, __HIP_MEMORY_SCOPE_AGENT) < target) {
          __builtin_amdgcn_s_sleep(4);
          if (__builtin_amdgcn_s_memrealtime() - t0 > 5000000ULL) break;  // ~50ms escape
        }
        __threadfence();  // acquire: invalidate stale lines
      }
      __syncthreads();
    }
  }
}

// ---------- fused GEMM: out = Xb (n x 768 bf16) @ W (768x128) + bsum ----------
#define BK 64
#define LDP (BK + 8)  // padded row stride in shorts
__global__ __launch_bounds__(256) void mfma_gemm_kernel(const short* __restrict__ Xb,
                                                        const short* __restrict__ Wt,
                                                        const float* __restrict__ bsum,
                                                        float* __restrict__ out, int n) {
  __shared__ short Al[64 * LDP];
  __shared__ short Bl[128 * LDP];
  int t = threadIdx.x;
  int w = t >> 6, lane = t & 63;
  int m = lane & 15, q = lane >> 4;
  int row0 = blockIdx.x * 64;
  int c0 = w * 32;

  f32x4 acc[4][2];
#pragma unroll
  for (int i = 0; i < 4; ++i)
#pragma unroll
    for (int j = 0; j < 2; ++j) acc[i][j] = (f32x4){0.f, 0.f, 0.f, 0.f};

  for (int k0 = 0; k0 < KD; k0 += BK) {
    __syncthreads();
#pragma unroll
    for (int p = 0; p < 2; ++p) {
      int idx = t + 256 * p;
      int r = idx >> 3, u = idx & 7;
      int gr = min(row0 + r, n - 1);
      short8 v = *(const short8*)(Xb + (size_t)gr * KD + k0 + u * 8);
      *(short8*)(Al + r * LDP + u * 8) = v;
    }
#pragma unroll
    for (int p = 0; p < 4; ++p) {
      int idx = t + 256 * p;
      int cc = idx >> 3, u = idx & 7;
      short8 v = *(const short8*)(Wt + (size_t)cc * KD + k0 + u * 8);
      *(short8*)(Bl + cc * LDP + u * 8) = v;
    }
    __syncthreads();
#pragma unroll
    for (int s = 0; s < 2; ++s) {
      int ko = s * 32 + q * 8;
      short8 b0 = *(const short8*)(Bl + (c0 + m) * LDP + ko);
      short8 b1 = *(const short8*)(Bl + (c0 + 16 + m) * LDP + ko);
#pragma unroll
      for (int rt = 0; rt < 4; ++rt) {
        short8 av = *(const short8*)(Al + (rt * 16 + m) * LDP + ko);
        acc[rt][0] = __builtin_amdgcn_mfma_f32_16x16x32_bf16(av, b0, acc[rt][0], 0, 0, 0);
        acc[rt][1] = __builtin_amdgcn_mfma_f32_16x16x32_bf16(av, b1, acc[rt][1], 0, 0, 0);
      }
    }
  }

#pragma unroll
  for (int ct = 0; ct < 2; ++ct) {
    int col = c0 + ct * 16 + m;
    float bs = bsum[col];
#pragma unroll
    for (int rt = 0; rt < 4; ++rt) {
#pragma unroll
      for (int i = 0; i < 4; ++i) {
        int row = row0 + rt * 16 + q * 4 + i;
        if (row < n) out[(size_t)row * C + col] = acc[rt][ct][i] + bs;
      }
    }
  }
}

extern "C" void kernel_launch(void* const* d_in, const int* in_sizes, int n_in,
                              void* d_out, int out_size, void* d_ws, size_t ws_size,
                              hipStream_t stream) {
  const float* nodes = (const float*)d_in[0];
  const float* edges = (const float*)d_in[1];
  const int* senders = (const int*)d_in[2];
  const int* receivers = (const int*)d_in[3];
  const float* W = (const float*)d_in[4];
  const float* b_dense = (const float*)d_in[5];
  const float* bias = (const float*)d_in[6];
  float* out = (float*)d_out;
  int n = in_sizes[0] / C;
  int ne = in_sizes[1];
  int NB = (ne + EPB - 1) / EPB;          // phase-1 blocks
  int NBUCK = (n + 255) >> 8;             // coarse buckets (sender>>8)
  int M = 256 * NB;                       // scan table length
  int nb2 = (M + 1023) / 1024;

  char* ws = (char*)d_ws;
  size_t off = 0;
  auto alloc = [&](size_t b) { size_t r = off; off += (b + 255) & ~(size_t)255; return r; };
  float* degf = (float*)(ws + alloc((size_t)n * 4));
  int* offsets = (int*)(ws + alloc((size_t)(n + 1) * 4));
  int* hist = (int*)(ws + alloc((size_t)M * 4));
  int* bsums = (int*)(ws + alloc((size_t)nb2 * 4));
  int2* bkt = (int2*)(ws + alloc((size_t)ne * 8));
  unsigned* csr = (unsigned*)(ws + alloc((size_t)ne * 4));  // u32 entries
  unsigned* umax = (unsigned*)(ws + alloc(8));  // [0]=umax, [1]=ticket
  int* bar = (int*)(ws + alloc(4));             // persistent barrier counter
  float* scalep = (float*)(ws + alloc(4));
  float* bsum = (float*)(ws + alloc(C * 4));
  short* Xb = (short*)(ws + alloc((size_t)n * KD * 2));
  short* Wt = (short*)(ws + alloc((size_t)KD * C * 2));
  (void)ws_size; (void)n_in; (void)out_size;

  // fused prep launch: Wt transpose + bias-sum + nodes->bf16 slot0 + zero flags
  int prep_n = max(KD * C, n * 32);
  prep_kernel<<<(prep_n + 255) / 256, 256, 0, stream>>>(W, b_dense, bias, Wt, bsum, nodes,
                                                        Xb, n, umax, bar);

  // CSR build — no global atomics (LDS atomics + scans only)
  p1_count_kernel<<<NB, 256, 0, stream>>>(senders, edges, ne, hist, NB, umax);
  scan1_kernel<<<nb2, 1024, 0, stream>>>(hist, hist, bsums, M);
  scan2_kernel<<<1, 1024, 0, stream>>>(bsums, nb2);
  p1_scatter_kernel<<<NB, 256, 0, stream>>>(senders, receivers, edges, ne, hist, bsums, NB, bkt);
  p2_finalize_kernel<<<NBUCK, 256, 0, stream>>>(bkt, hist, bsums, NB, NBUCK, ne, n, csr,
                                                offsets, degf, umax, (int*)(umax + 1), scalep);

  // 5 Chebyshev rounds in ONE persistent launch (normal launch, graph-safe)
  matvec5_kernel<<<NPBLK, 256, 0, stream>>>(Xb, degf, offsets, csr, scalep, n, bar);

  // out = Xb @ vstack(W) + (sum_k b_k + bias), LDS-staged MFMA GEMM
  mfma_gemm_kernel<<<(n + 63) / 64, 256, 0, stream>>>(Xb, Wt, bsum, out, n);
}

// Round 6
// 366.328 us; speedup vs baseline: 5.2960x; 5.2960x over previous
//
#include <hip/hip_runtime.h>
#include <hip/hip_fp16.h>

#define C 128
#define KORD 6
#define KD (KORD * C)  // 768 fused reduction dim
#define EPB 2048       // edges per block in phase-1

typedef __attribute__((ext_vector_type(8))) short short8;   // 8 bf16
typedef __attribute__((ext_vector_type(4))) float f32x4;

// ---------- fp32 -> bf16 (RNE) ----------
__device__ __forceinline__ short f2bf(float f) {
  unsigned u = __float_as_uint(f);
  unsigned r = (u + 0x7fffu + ((u >> 16) & 1u)) >> 16;
  return (short)r;
}
__device__ __forceinline__ float bf2f(short s) {
  return __uint_as_float(((unsigned)(unsigned short)s) << 16);
}

// ---------- monotone float<->uint encoding for atomicMax over floats ----------
__device__ __forceinline__ unsigned enc_f32(float f) {
  unsigned u = __float_as_uint(f);
  return (u & 0x80000000u) ? ~u : (u | 0x80000000u);
}
__device__ __forceinline__ float dec_f32(unsigned u) {
  return (u & 0x80000000u) ? __uint_as_float(u ^ 0x80000000u) : __uint_as_float(~u);
}

// ============================================================================
// State layout (R6): each Chebyshev slot s in [0,6] is TWO COMPACT half-buffers
// of n x 64 channels (n x 128 B), at Xb + (2s+h)*n64 shorts. A per-edge gather
// is one 128-B row = exactly one cache line, 100% utilized, from a 6.4 MB hot
// set (vs 12.8 MB) -> higher per-XCD L2 hit rate. Matvec is L3->L2 fill-rate
// bound (R5 analysis: ~0.7 TB/s/XCD), so footprint is the only lever.
// ============================================================================

// ---------- fused: Wt transpose + bsum + nodes->bf16 slot0-halves + zero flags ----------
__global__ void prep_kernel(const float* __restrict__ W, const float* __restrict__ bd,
                            const float* __restrict__ bias, short* __restrict__ Wt,
                            float* __restrict__ bsum, const float* __restrict__ nodes,
                            short* __restrict__ xb, int n, unsigned* __restrict__ umax) {
  int i = blockIdx.x * blockDim.x + threadIdx.x;
  if (i == 0) {
    umax[0] = 0u;   // running max (enc)
    umax[1] = 0u;   // ticket
  }
  if (i < KD * C) {
    int k = i >> 7, nn = i & 127;
    Wt[(size_t)nn * KD + k] = f2bf(W[i]);
  }
  if (i < C) {
    float s = bias[i];
#pragma unroll
    for (int k = 0; k < KORD; ++k) s += bd[k * C + i];
    bsum[i] = s;
  }
  if (i < n * 32) {
    int row = i >> 5, c4 = i & 31;
    float4 v = ((const float4*)nodes)[(size_t)row * 32 + c4];
    short4 o;
    o.x = f2bf(v.x); o.y = f2bf(v.y); o.z = f2bf(v.z); o.w = f2bf(v.w);
    int h = c4 >> 4;          // which 64-ch half
    int cc = c4 & 15;         // short4 slot within the half-row
    ((short4*)(xb + (size_t)h * ((size_t)n * 64) + (size_t)row * 64))[cc] = o;
  }
}

// ---------- phase 1a: coarse bucket histogram (LDS atomics only) + max(-w) ----------
__global__ __launch_bounds__(256) void p1_count_kernel(const int* __restrict__ senders,
                                                       const float* __restrict__ edges, int ne,
                                                       int* __restrict__ hist, int NB,
                                                       unsigned* __restrict__ umax) {
  __shared__ int h[256];
  int t = threadIdx.x;
  h[t] = 0;
  __syncthreads();
  int base = blockIdx.x * EPB;
  int end = min(base + EPB, ne);
  float m = -INFINITY;
  for (int i = base + t; i < end; i += 256) {
    atomicAdd(&h[senders[i] >> 8], 1);
    m = fmaxf(m, -edges[i]);
  }
#pragma unroll
  for (int off = 32; off > 0; off >>= 1) m = fmaxf(m, __shfl_down(m, off, 64));
  if ((t & 63) == 0) atomicMax(umax, enc_f32(m));
  __syncthreads();
  hist[t * NB + blockIdx.x] = h[t];
}

// ---------- multiblock exclusive scan, stage 1 ----------
__global__ __launch_bounds__(1024) void scan1_kernel(const int* __restrict__ counts,
                                                     int* __restrict__ offsets,
                                                     int* __restrict__ bsums, int n) {
  int t = threadIdx.x;
  int i = blockIdx.x * 1024 + t;
  int lane = t & 63, w = t >> 6;
  int v = (i < n) ? counts[i] : 0;
  int s = v;
#pragma unroll
  for (int d = 1; d < 64; d <<= 1) {
    int o = __shfl_up(s, d, 64);
    if (lane >= d) s += o;
  }
  __shared__ int wsum[16];
  if (lane == 63) wsum[w] = s;
  __syncthreads();
  if (t < 16) {
    int ws = wsum[t];
#pragma unroll
    for (int d = 1; d < 16; d <<= 1) {
      int o = __shfl_up(ws, d, 64);
      if (t >= d) ws += o;
    }
    wsum[t] = ws;
  }
  __syncthreads();
  int excl = s - v + (w > 0 ? wsum[w - 1] : 0);
  if (i < n) offsets[i] = excl;
  if (t == 1023) bsums[blockIdx.x] = wsum[15];
}

// ---------- stage 2: scan of block sums (nb <= 1024) ----------
__global__ __launch_bounds__(1024) void scan2_kernel(int* __restrict__ bsums, int nb) {
  int t = threadIdx.x;
  int lane = t & 63, w = t >> 6;
  int v = (t < nb) ? bsums[t] : 0;
  int s = v;
#pragma unroll
  for (int d = 1; d < 64; d <<= 1) {
    int o = __shfl_up(s, d, 64);
    if (lane >= d) s += o;
  }
  __shared__ int wsum[16];
  if (lane == 63) wsum[w] = s;
  __syncthreads();
  if (t < 16) {
    int ws = wsum[t];
#pragma unroll
    for (int d = 1; d < 16; d <<= 1) {
      int o = __shfl_up(ws, d, 64);
      if (t >= d) ws += o;
    }
    wsum[t] = ws;
  }
  __syncthreads();
  int excl = s - v + (w > 0 ? wsum[w - 1] : 0);
  if (t < nb) bsums[t] = excl;
}

// ---------- phase 1b: scatter into coarse buckets; applies bsums (scan3 folded) ----------
__global__ __launch_bounds__(256) void p1_scatter_kernel(
    const int* __restrict__ senders, const int* __restrict__ receivers,
    const float* __restrict__ edges, int ne, const int* __restrict__ scanned,
    const int* __restrict__ bsums, int NB, int2* __restrict__ bkt) {
  __shared__ int basec[256];
  int t = threadIdx.x;
  int idx = t * NB + blockIdx.x;
  basec[t] = scanned[idx] + bsums[idx >> 10];
  __syncthreads();
  int base = blockIdx.x * EPB;
  int end = min(base + EPB, ne);
  for (int i = base + t; i < end; i += 256) {
    int s = senders[i];
    int pos = atomicAdd(&basec[s >> 8], 1);
    int2 rec;
    rec.x = __float_as_int(edges[i]);
    rec.y = receivers[i] | ((s & 255) << 16);
    bkt[pos] = rec;
  }
}

// ---------- phase 2: CSR finalize + offsets + deg + deg-max + (last block) scale ----------
// csr entry is 32 bits: [w_f16 << 16 | recv_u16]. deg accumulates the
// f16-ROUNDED weight (perturbed-graph consistency, err ~2^-12).
__global__ __launch_bounds__(256) void p2_finalize_kernel(
    const int2* __restrict__ bkt, const int* __restrict__ scanned,
    const int* __restrict__ bsums, int NB, int NBUCK, int ne, int n,
    unsigned* __restrict__ csr_wr, int* __restrict__ offsets, float* __restrict__ degf,
    unsigned* __restrict__ umax, int* __restrict__ ticket, float* __restrict__ scalep) {
  __shared__ int h[256];
  __shared__ int cur[256];
  __shared__ float dg[256];
  __shared__ int wsum[4];
  __shared__ float wmax[4];
  int t = threadIdx.x;
  int b = blockIdx.x;
  int i0 = b * NB;
  int base = scanned[i0] + bsums[i0 >> 10];
  int bend = ne;
  if (b != NBUCK - 1) {
    int i1 = (b + 1) * NB;
    bend = scanned[i1] + bsums[i1 >> 10];
  }
  h[t] = 0;
  dg[t] = 0.f;
  __syncthreads();
  for (int i = base + t; i < bend; i += 256) atomicAdd(&h[(bkt[i].y >> 16) & 255], 1);
  __syncthreads();
  int lane = t & 63, w = t >> 6;
  int v = h[t];
  int s = v;
#pragma unroll
  for (int d = 1; d < 64; d <<= 1) {
    int o = __shfl_up(s, d, 64);
    if (lane >= d) s += o;
  }
  if (lane == 63) wsum[w] = s;
  __syncthreads();
  int carry = 0;
#pragma unroll
  for (int j = 0; j < 4; ++j) carry += (j < w) ? wsum[j] : 0;
  int excl = s - v + carry;
  int node = b * 256 + t;
  if (node < n) offsets[node] = base + excl;
  cur[t] = base + excl;
  __syncthreads();
  for (int i = base + t; i < bend; i += 256) {
    int2 rec = bkt[i];
    int bin = (rec.y >> 16) & 255;
    int pos = atomicAdd(&cur[bin], 1);
    __half hh = __float2half(__int_as_float(rec.x));
    csr_wr[pos] = (unsigned)(rec.y & 0xFFFF) | ((unsigned)__half_as_ushort(hh) << 16);
    atomicAdd(&dg[bin], __half2float(hh));
  }
  __syncthreads();
  float d = dg[t];
  if (node < n) degf[node] = d;
  float m = (node < n) ? d : 0.f;
#pragma unroll
  for (int off = 32; off > 0; off >>= 1) m = fmaxf(m, __shfl_down(m, off, 64));
  if (lane == 0) wmax[w] = m;
  __syncthreads();
  if (t == 0) {
    float mm = fmaxf(fmaxf(wmax[0], wmax[1]), fmaxf(wmax[2], wmax[3]));
    atomicMax(umax, enc_f32(mm));
    if (b == NBUCK - 1) offsets[n] = ne;
    __threadfence();  // publish umax before taking a ticket
    int done = atomicAdd(ticket, 1);
    if (done == NBUCK - 1) {
      unsigned cu = atomicMax(umax, 0u);
      scalep[0] = 1.0f / dec_f32(cu);
    }
  }
}

// ---------- Tx_k = coef*scale*(deg*x - A x) - z, compact-half bf16 state ----------
// One launch per round, TWO independent channel-half passes selected by
// blockIdx range (dispatch is ~monotonic in blockIdx -> temporal separation;
// passes are data-independent so mixing is merely a locality perturbation).
// Per wave: one node; 8 groups x 8 lanes x short8; each group gathers one
// edge's 128-B half-row (exactly one cache line); 2-deep predicated batch ->
// 16 gathers in flight per wave (same as R3). Reduce = shfl_xor 8/16/32.
__global__ __launch_bounds__(256, 8) void matvec_kernel(
    const short* __restrict__ xh,   // slot r base (2 halves)
    const short* __restrict__ zh,   // slot r-1 base or nullptr
    short* __restrict__ yh,         // slot r+1 base
    const float* __restrict__ deg, const int* __restrict__ offsets,
    const unsigned* __restrict__ csr_wr, const float* __restrict__ scalep,
    float coef, int n, int pblocks) {
  int b = blockIdx.x;
  int h = (b >= pblocks) ? 1 : 0;
  int wid = ((b - h * pblocks) * 256 + threadIdx.x) >> 6;  // node
  if (wid >= n) return;
  int lane = threadIdx.x & 63;
  int g = lane >> 3;       // edge group 0..7
  int sub = lane & 7;      // 8 lanes x short8 = 64 ch
  size_t n64 = (size_t)n * 64;
  const short* xg = xh + (size_t)h * n64;
  const short* zg = zh ? zh + (size_t)h * n64 : (const short*)0;
  short* yg = yh + (size_t)h * n64;
  float sc = scalep[0] * coef;
  int e0 = offsets[wid], e1 = offsets[wid + 1];
  // hoisted epilogue operands (group 0 only; exec-masked loads overlap gathers)
  float d = 0.f;
  short8 xo = {0, 0, 0, 0, 0, 0, 0, 0};
  short8 zv = {0, 0, 0, 0, 0, 0, 0, 0};
  if (g == 0) {
    d = deg[wid];
    xo = *(const short8*)(xg + (size_t)wid * 64 + sub * 8);
    if (zg) zv = *(const short8*)(zg + (size_t)wid * 64 + sub * 8);
  }
  float a[8];
#pragma unroll
  for (int j = 0; j < 8; ++j) a[j] = 0.f;
  int elast = e1 - 1;
  const short* xs = xg + sub * 8;
  for (int e = e0 + g; e < e1; e += 16) {
    int e2 = e + 8;
    unsigned p0 = csr_wr[e];
    unsigned p1 = csr_wr[min(e2, elast)];
    short8 v0 = *(const short8*)(xs + (p0 & 0xFFFFu) * 64);
    short8 v1 = *(const short8*)(xs + (p1 & 0xFFFFu) * 64);
    float w0 = __half2float(__ushort_as_half((unsigned short)(p0 >> 16)));
    float w1 = (e2 < e1) ? __half2float(__ushort_as_half((unsigned short)(p1 >> 16))) : 0.f;
#pragma unroll
    for (int j = 0; j < 8; ++j) {
      float t0 = fmaf(w0, bf2f(v0[j]), a[j]);
      a[j] = fmaf(w1, bf2f(v1[j]), t0);
    }
  }
  // combine the 8 edge groups (lanes with equal sub)
#pragma unroll
  for (int j = 0; j < 8; ++j) {
    a[j] += __shfl_xor(a[j], 8, 64);
    a[j] += __shfl_xor(a[j], 16, 64);
    a[j] += __shfl_xor(a[j], 32, 64);
  }
  if (g == 0) {
    float r[8];
#pragma unroll
    for (int j = 0; j < 8; ++j) r[j] = sc * fmaf(d, bf2f(xo[j]), -a[j]);
    if (zg) {
#pragma unroll
      for (int j = 0; j < 8; ++j) r[j] -= bf2f(zv[j]);
    }
    short8 o;
#pragma unroll
    for (int j = 0; j < 8; ++j) o[j] = f2bf(r[j]);
    *(short8*)(yg + (size_t)wid * 64 + sub * 8) = o;
  }
}

// ---------- fused GEMM: out = X (n x 768 bf16, half-buffer layout) @ W + bsum ----------
// A k-block of BK=64 is EXACTLY one compact half-buffer: buffer idx = k0>>6.
#define BK 64
#define LDP (BK + 8)  // padded row stride in shorts
__global__ __launch_bounds__(256) void mfma_gemm_kernel(const short* __restrict__ Xb,
                                                        const short* __restrict__ Wt,
                                                        const float* __restrict__ bsum,
                                                        float* __restrict__ out, int n) {
  __shared__ short Al[64 * LDP];
  __shared__ short Bl[128 * LDP];
  int t = threadIdx.x;
  int w = t >> 6, lane = t & 63;
  int m = lane & 15, q = lane >> 4;
  int row0 = blockIdx.x * 64;
  int c0 = w * 32;
  size_t n64 = (size_t)n * 64;

  f32x4 acc[4][2];
#pragma unroll
  for (int i = 0; i < 4; ++i)
#pragma unroll
    for (int j = 0; j < 2; ++j) acc[i][j] = (f32x4){0.f, 0.f, 0.f, 0.f};

  for (int k0 = 0; k0 < KD; k0 += BK) {
    const short* Ab = Xb + (size_t)(k0 >> 6) * n64;  // compact half-buffer
    __syncthreads();
#pragma unroll
    for (int p = 0; p < 2; ++p) {
      int idx = t + 256 * p;
      int r = idx >> 3, u = idx & 7;
      int gr = min(row0 + r, n - 1);
      short8 v = *(const short8*)(Ab + (size_t)gr * 64 + u * 8);
      *(short8*)(Al + r * LDP + u * 8) = v;
    }
#pragma unroll
    for (int p = 0; p < 4; ++p) {
      int idx = t + 256 * p;
      int cc = idx >> 3, u = idx & 7;
      short8 v = *(const short8*)(Wt + (size_t)cc * KD + k0 + u * 8);
      *(short8*)(Bl + cc * LDP + u * 8) = v;
    }
    __syncthreads();
#pragma unroll
    for (int s = 0; s < 2; ++s) {
      int ko = s * 32 + q * 8;
      short8 b0 = *(const short8*)(Bl + (c0 + m) * LDP + ko);
      short8 b1 = *(const short8*)(Bl + (c0 + 16 + m) * LDP + ko);
#pragma unroll
      for (int rt = 0; rt < 4; ++rt) {
        short8 av = *(const short8*)(Al + (rt * 16 + m) * LDP + ko);
        acc[rt][0] = __builtin_amdgcn_mfma_f32_16x16x32_bf16(av, b0, acc[rt][0], 0, 0, 0);
        acc[rt][1] = __builtin_amdgcn_mfma_f32_16x16x32_bf16(av, b1, acc[rt][1], 0, 0, 0);
      }
    }
  }

#pragma unroll
  for (int ct = 0; ct < 2; ++ct) {
    int col = c0 + ct * 16 + m;
    float bs = bsum[col];
#pragma unroll
    for (int rt = 0; rt < 4; ++rt) {
#pragma unroll
      for (int i = 0; i < 4; ++i) {
        int row = row0 + rt * 16 + q * 4 + i;
        if (row < n) out[(size_t)row * C + col] = acc[rt][ct][i] + bs;
      }
    }
  }
}

extern "C" void kernel_launch(void* const* d_in, const int* in_sizes, int n_in,
                              void* d_out, int out_size, void* d_ws, size_t ws_size,
                              hipStream_t stream) {
  const float* nodes = (const float*)d_in[0];
  const float* edges = (const float*)d_in[1];
  const int* senders = (const int*)d_in[2];
  const int* receivers = (const int*)d_in[3];
  const float* W = (const float*)d_in[4];
  const float* b_dense = (const float*)d_in[5];
  const float* bias = (const float*)d_in[6];
  float* out = (float*)d_out;
  int n = in_sizes[0] / C;
  int ne = in_sizes[1];
  int NB = (ne + EPB - 1) / EPB;          // phase-1 blocks
  int NBUCK = (n + 255) >> 8;             // coarse buckets (sender>>8)
  int M = 256 * NB;                       // scan table length
  int nb2 = (M + 1023) / 1024;

  char* ws = (char*)d_ws;
  size_t off = 0;
  auto alloc = [&](size_t b) { size_t r = off; off += (b + 255) & ~(size_t)255; return r; };
  float* degf = (float*)(ws + alloc((size_t)n * 4));
  int* offsets = (int*)(ws + alloc((size_t)(n + 1) * 4));
  int* hist = (int*)(ws + alloc((size_t)M * 4));
  int* bsums = (int*)(ws + alloc((size_t)nb2 * 4));
  int2* bkt = (int2*)(ws + alloc((size_t)ne * 8));
  unsigned* csr = (unsigned*)(ws + alloc((size_t)ne * 4));  // u32 entries
  unsigned* umax = (unsigned*)(ws + alloc(8));  // [0]=umax, [1]=ticket
  float* scalep = (float*)(ws + alloc(4));
  float* bsum = (float*)(ws + alloc(C * 4));
  short* Xb = (short*)(ws + alloc((size_t)n * KD * 2));  // 12 compact half-buffers
  short* Wt = (short*)(ws + alloc((size_t)KD * C * 2));
  (void)ws_size; (void)n_in; (void)out_size;

  size_t n64 = (size_t)n * 64;

  // fused prep launch: Wt transpose + bias-sum + nodes->bf16 slot0 + zero flags
  int prep_n = max(KD * C, n * 32);
  prep_kernel<<<(prep_n + 255) / 256, 256, 0, stream>>>(W, b_dense, bias, Wt, bsum, nodes,
                                                        Xb, n, umax);

  // CSR build — no global atomics (LDS atomics + scans only)
  p1_count_kernel<<<NB, 256, 0, stream>>>(senders, edges, ne, hist, NB, umax);
  scan1_kernel<<<nb2, 1024, 0, stream>>>(hist, hist, bsums, M);
  scan2_kernel<<<1, 1024, 0, stream>>>(bsums, nb2);
  p1_scatter_kernel<<<NB, 256, 0, stream>>>(senders, receivers, edges, ne, hist, bsums, NB, bkt);
  p2_finalize_kernel<<<NBUCK, 256, 0, stream>>>(bkt, hist, bsums, NB, NBUCK, ne, n, csr,
                                                offsets, degf, umax, (int*)(umax + 1), scalep);

  int pblocks = (n * 64 + 255) / 256;   // blocks per channel-half pass
  int mvblocks = 2 * pblocks;           // both halves in one launch

  // Chebyshev recurrence on compact half-buffers (slot s at Xb + 2*s*n64):
  for (int r = 0; r < 5; ++r) {
    const short* xh = Xb + (size_t)(2 * r) * n64;
    const short* zh = (r == 0) ? (const short*)nullptr : Xb + (size_t)(2 * (r - 1)) * n64;
    short* yh = Xb + (size_t)(2 * (r + 1)) * n64;
    matvec_kernel<<<mvblocks, 256, 0, stream>>>(xh, zh, yh, degf, offsets, csr, scalep,
                                                (r == 0) ? 1.0f : 2.0f, n, pblocks);
  }

  // out = X @ vstack(W) + (sum_k b_k + bias), LDS-staged MFMA GEMM
  mfma_gemm_kernel<<<(n + 63) / 64, 256, 0, stream>>>(Xb, Wt, bsum, out, n);
}